// Round 16
// baseline (241.123 us; speedup 1.0000x reference)
//
#include <hip/hip_runtime.h>
#include <math.h>

// NSA attention (round 28: sel rank-scan via readlane broadcasts (-16 KB LDS
// -> 4 blocks/CU) + exp-write bank fix. Round 27 counters: attn_fused 128 us,
// occ 33%, bank conflicts 1.58M (new, from the exp phase: rotation (i+row)
// de-conflicts rows but for a fixed row the 8 key-groups hit only 2 banks ->
// 4-way). Fixes:
//  1. rank scan needs only "my ordinal vs all cnt ordinals"; candidates live
//     one-per-lane in regs, so __shfl(ord, i) with uniform i (v_readlane ->
//     SGPR broadcast) replaces the LDS ords array + 2 lgkmcnt barriers.
//     Semantics identical (loop i<min(cnt,64) on slot A; rare loop for B).
//     Deletes ords[8][128] (16 KB): sel arena 45824 -> 37632 B -> 4 blocks/CU
//     = 32 waves (hw max) for ALL roles (+33% latency hiding).
//  2. exp-phase rotation key = kg + ((i + row + (kg>>4)) & 15): banks
//     (key+row)%32 now distinct across rows AND key-groups (parity split by
//     +-16). Still a per-thread bijection -> bit-exact.
// All else byte-identical to r27 (verified: -5 margin superset, bit-plane
// compact, exact ordinal rank scan = exact jax (val desc, key asc) order).
// B=2 L=2048 C=256 H=8 HD=32 BS=16 SK=16 win=+-32.

#define Bc 2
#define Lc 2048
#define Cc 256
#define Hc 8
#define HDc 32
#define BHc 16          // B*H
#define NBc 128         // L/BS
#define ROWSc 4096      // B*L
#define TROWSc 32768    // B*H*L
#define SCALEc 0.17677669529663687f

typedef unsigned long long u64;
typedef __attribute__((ext_vector_type(8))) short short8v;   // 8 bf16
typedef __attribute__((ext_vector_type(4))) float f32x4;

// ---------- helpers ----------

__device__ __forceinline__ float dot32q(const float* qr, const float* kr) {
  const float4* k4 = (const float4*)kr;
  float p0 = 0.f, p1 = 0.f, p2 = 0.f, p3 = 0.f;
#pragma unroll
  for (int j = 0; j < 8; j += 4) {
    float4 a = k4[j], b = k4[j + 1], c = k4[j + 2], e = k4[j + 3];
    p0 += a.x * qr[4 * j + 0] + a.y * qr[4 * j + 1] + a.z * qr[4 * j + 2] + a.w * qr[4 * j + 3];
    p1 += b.x * qr[4 * j + 4] + b.y * qr[4 * j + 5] + b.z * qr[4 * j + 6] + b.w * qr[4 * j + 7];
    p2 += c.x * qr[4 * j + 8] + c.y * qr[4 * j + 9] + c.z * qr[4 * j + 10] + c.w * qr[4 * j + 11];
    p3 += e.x * qr[4 * j + 12] + e.y * qr[4 * j + 13] + e.z * qr[4 * j + 14] + e.w * qr[4 * j + 15];
  }
  return (p0 + p1) + (p2 + p3);
}

__device__ __forceinline__ unsigned short bf16rne(float f) {
  const unsigned u = __float_as_uint(f);
  return (unsigned short)((u + 0x7fffu + ((u >> 16) & 1u)) >> 16);
}

// order-preserving float->int map
__device__ __forceinline__ int f2o(float x) {
  const int i = __float_as_int(x);
  return i >= 0 ? i : (i ^ 0x7fffffff);
}

// broadcast lane src's 64-bit value (src wave-uniform -> v_readlane)
__device__ __forceinline__ u64 bcast64(u64 v, int src) {
  const int lo = __shfl((int)(unsigned)(v & 0xffffffffull), src);
  const int hi = __shfl((int)(unsigned)(v >> 32), src);
  return ((u64)(unsigned)hi << 32) | (u64)(unsigned)lo;
}

// ---------- projections ----------
// X(4096,256) @ W(256,256) + bias. headlayout=1: store [b*H+h][l][d]; else [row][c].
__global__ __launch_bounds__(256) void proj_kernel(const float* __restrict__ X,
                                                   const float* __restrict__ W,
                                                   const float* __restrict__ bias,
                                                   float* __restrict__ outp, int headlayout) {
  __shared__ float xs[8 * Cc];
  const int tid = threadIdx.x;
  const int row0 = blockIdx.x * 8;
  {
    const float4* xin = (const float4*)(X + (size_t)row0 * Cc);
    float4* xsv = (float4*)xs;
    xsv[tid] = xin[tid];
    xsv[tid + 256] = xin[tid + 256];
  }
  __syncthreads();
  const int c0 = (tid & 63) * 4;  // 4 consecutive cols
  const int rh = tid >> 6;        // wave id; 2 rows per wave
  float acc[2][4];
#pragma unroll
  for (int r = 0; r < 2; ++r)
#pragma unroll
    for (int c = 0; c < 4; ++c) acc[r][c] = 0.f;

#pragma unroll 4
  for (int d4 = 0; d4 < 64; ++d4) {
    const int d = d4 * 4;
    const float4 w0 = *(const float4*)(W + (size_t)(d + 0) * Cc + c0);
    const float4 w1 = *(const float4*)(W + (size_t)(d + 1) * Cc + c0);
    const float4 w2 = *(const float4*)(W + (size_t)(d + 2) * Cc + c0);
    const float4 w3 = *(const float4*)(W + (size_t)(d + 3) * Cc + c0);
#pragma unroll
    for (int r = 0; r < 2; ++r) {
      const float4 xv = *(const float4*)(xs + (rh * 2 + r) * Cc + d);
      acc[r][0] += xv.x * w0.x + xv.y * w1.x + xv.z * w2.x + xv.w * w3.x;
      acc[r][1] += xv.x * w0.y + xv.y * w1.y + xv.z * w2.y + xv.w * w3.y;
      acc[r][2] += xv.x * w0.z + xv.y * w1.z + xv.z * w2.z + xv.w * w3.z;
      acc[r][3] += xv.x * w0.w + xv.y * w1.w + xv.z * w2.w + xv.w * w3.w;
    }
  }
  const float4 bv = *(const float4*)(bias + c0);
#pragma unroll
  for (int r = 0; r < 2; ++r) {
    const int grow = row0 + rh * 2 + r;
    const float4 o = make_float4(acc[r][0] + bv.x, acc[r][1] + bv.y,
                                 acc[r][2] + bv.z, acc[r][3] + bv.w);
    if (headlayout) {
      const int b = grow >> 11, l = grow & 2047;
      const int h = c0 >> 5, dd = c0 & 31;
      *(float4*)(outp + (((size_t)(b * Hc + h) * Lc + l) * HDc + dd)) = o;
    } else {
      *(float4*)(outp + (size_t)grow * Cc + c0) = o;
    }
  }
}

// gate = sigmoid(query @ Wg + bg), one thread per row
__global__ __launch_bounds__(256) void gate_kernel(const float* __restrict__ query,
                                                   const float* __restrict__ Wg,
                                                   const float* __restrict__ bg,
                                                   float* __restrict__ gatep) {
  const int row = blockIdx.x * 256 + threadIdx.x;
  const float4* x4 = (const float4*)(query + (size_t)row * Cc);
  float a0 = bg[0], a1 = bg[1], a2 = bg[2];
#pragma unroll 8
  for (int d4 = 0; d4 < 64; ++d4) {
    const float4 xv = x4[d4];
    const float* wr = Wg + d4 * 12;
    a0 += xv.x * wr[0] + xv.y * wr[3] + xv.z * wr[6] + xv.w * wr[9];
    a1 += xv.x * wr[1] + xv.y * wr[4] + xv.z * wr[7] + xv.w * wr[10];
    a2 += xv.x * wr[2] + xv.y * wr[5] + xv.z * wr[8] + xv.w * wr[11];
  }
  float* g = gatep + (size_t)row * 3;
  g[0] = 1.f / (1.f + __expf(-a0));
  g[1] = 1.f / (1.f + __expf(-a1));
  g[2] = 1.f / (1.f + __expf(-a2));
}

// ---------- compressed K/V ----------
__global__ __launch_bounds__(256) void cmpkv_kernel(const float* __restrict__ kh,
                                                    const float* __restrict__ vh,
                                                    const float* __restrict__ WKc,
                                                    const float* __restrict__ WVc,
                                                    const float* __restrict__ Wpe,
                                                    float* __restrict__ Kcp,
                                                    float* __restrict__ Vcp) {
  const int idx = blockIdx.x * 256 + threadIdx.x;  // 65536 = bh*128*32
  const int d = idx & 31, n = (idx >> 5) & 127, bh = idx >> 12;
  float pk = 0.f, pv = 0.f;
#pragma unroll
  for (int s = 0; s < 16; ++s) {
    const float pe = Wpe[s * Cc + d];
    pk += pe * WKc[s];
    pv += pe * WVc[s];
  }
  const float* kp = kh + ((size_t)bh * Lc + n * 16) * HDc + d;
  const float* vp = vh + ((size_t)bh * Lc + n * 16) * HDc + d;
  float ak = pk, av = pv;
#pragma unroll
  for (int s = 0; s < 16; ++s) {
    ak += kp[s * HDc] * WKc[s];
    av += vp[s * HDc] * WVc[s];
  }
  Kcp[idx] = ak;
  Vcp[idx] = av;
}

// ---------- f32 -> bf16 (rne) for qh, kh ----------
__global__ __launch_bounds__(256) void cvtbf16_kernel(const float* __restrict__ qh,
                                                      const float* __restrict__ kh,
                                                      unsigned short* __restrict__ qhb,
                                                      unsigned short* __restrict__ khb) {
  const int gid = blockIdx.x * 256 + threadIdx.x;  // 0..524288
  const int half = (TROWSc * HDc) / 4;             // 262144 float4-groups
  const float* src = gid < half ? qh : kh;
  unsigned short* dst = gid < half ? qhb : khb;
  const int i = (gid < half ? gid : gid - half) * 4;
  const float4 v = *(const float4*)(src + i);
  ushort4 o;
  o.x = bf16rne(v.x);
  o.y = bf16rne(v.y);
  o.z = bf16rne(v.z);
  o.w = bf16rne(v.w);
  *(ushort4*)(dst + i) = o;
}

// ================== fused attention (role-switched) ==================
// LDS arena layout:
//   sel role : pnl[16][2064] (33024) | candv[8][16] (512) | candk[8][128]
//              (4096)                               = 37632 B
//   cmp/win  : sc[128][65] (33280) | pm[8][64] (2048) = 35328 B
// -> 4 blocks/CU (32 waves, hw max) for all roles.
#define SMEM_BYTES 37632

// ---- cmp_attn role (r27 + r28 exp-write bank fix) ----
__device__ void cmp_attn_body(unsigned char* smraw, int bx, int bh,
                              const float* __restrict__ qh,
                              const float* __restrict__ Kcp,
                              const float* __restrict__ Vcp,
                              float* __restrict__ ocmp) {
  float (*sc)[65] = (float(*)[65])smraw;
  float (*pm)[64] = (float(*)[64])(smraw + 33280);
  const int tid = threadIdx.x, lane = tid & 63;
  const int w = __builtin_amdgcn_readfirstlane(tid >> 6);
  const int lrow = bx * 64 + lane;
  const float* q = qh + ((size_t)bh * Lc + lrow) * HDc;
  float qr[HDc];
#pragma unroll
  for (int d = 0; d < HDc; ++d) qr[d] = q[d] * SCALEc;
  const float* kcb = Kcp + (size_t)bh * NBc * HDc;
  float pmax = -1e30f;
#pragma unroll
  for (int i = 0; i < 16; ++i) {
    const int key = w * 16 + i;  // uniform
    const float s = dot32q(qr, kcb + (size_t)key * HDc);
    sc[key][lane] = s;
    pmax = fmaxf(pmax, s);
  }
  pm[w][lane] = pmax;
  __syncthreads();

  const int row = tid >> 3;        // 0..63
  const int kg = (tid & 7) * 16;   // key-group base for exp phase
  const int rot = row + (tid & 7); // bank-spread rotation (r28)
  float m = pm[0][row];
#pragma unroll
  for (int i = 1; i < 8; ++i) m = fmaxf(m, pm[i][row]);
  // one-shot exp: 16 keys/thread, overwrite sc in place (2-way banks)
#pragma unroll
  for (int i = 0; i < 16; ++i) {
    const int key = kg + ((i + rot) & 15);
    sc[key][row] = __expf(sc[key][row] - m);
  }
  __syncthreads();

  const int dg = (tid & 7) * 4;    // dim-group base
  const float* vcb = Vcp + (size_t)bh * NBc * HDc + dg;
  float o0a = 0.f, o1a = 0.f, o2a = 0.f, o3a = 0.f, za = 0.f;
  float o0b = 0.f, o1b = 0.f, o2b = 0.f, o3b = 0.f, zb = 0.f;
#pragma unroll 4
  for (int key = 0; key < 128; key += 2) {
    const float wa = sc[key][row];
    const float wb = sc[key + 1][row];
    za += wa; zb += wb;
    const float4 va = *(const float4*)(vcb + key * HDc);
    const float4 vv = *(const float4*)(vcb + (key + 1) * HDc);
    o0a += wa * va.x; o1a += wa * va.y; o2a += wa * va.z; o3a += wa * va.w;
    o0b += wb * vv.x; o1b += wb * vv.y; o2b += wb * vv.z; o3b += wb * vv.w;
  }
  const float iz = 1.f / (za + zb);
  *(float4*)(ocmp + ((size_t)bh * Lc + bx * 64 + row) * HDc + dg) =
      make_float4((o0a + o0b) * iz, (o1a + o1b) * iz, (o2a + o2b) * iz,
                  (o3a + o3b) * iz);
}

// ---- win_attn role (r27 + r28 exp-write bank fix) ----
__device__ void win_attn_body(unsigned char* smraw, int bx, int bh,
                              const float* __restrict__ qh,
                              const float* __restrict__ kh,
                              const float* __restrict__ vh,
                              float* __restrict__ owin) {
  float (*sc)[65] = (float(*)[65])smraw;
  float (*pm)[64] = (float(*)[64])(smraw + 33280);
  const int tid = threadIdx.x, lane = tid & 63;
  const int w = __builtin_amdgcn_readfirstlane(tid >> 6);
  const int l0 = bx * 64;
  const int lrow = l0 + lane;
  const float* q = qh + ((size_t)bh * Lc + lrow) * HDc;
  float qr[HDc];
#pragma unroll
  for (int d = 0; d < HDc; ++d) qr[d] = q[d] * SCALEc;
  const float* kb = kh + (size_t)bh * Lc * HDc;
  float pmax = -1e30f;
#pragma unroll
  for (int i = 0; i < 16; ++i) {
    const int j = w * 16 + i;            // 0..127 (uniform)
    const int key = l0 - 32 + j;         // absolute key (uniform)
    const int keyc = min(max(key, 0), Lc - 1);  // uniform clamp for the load
    float s = dot32q(qr, kb + (size_t)keyc * HDc);
    const int delta = key - lrow;        // lane-varying
    const bool ok = (key >= 0) && (key < Lc) && (delta >= -32) && (delta <= 32);
    s = ok ? s : -1e30f;
    sc[j][lane] = s;
    pmax = fmaxf(pmax, s);
  }
  pm[w][lane] = pmax;
  __syncthreads();

  const int row = tid >> 3;
  const int kg = (tid & 7) * 16;
  const int rot = row + (tid & 7);  // bank-spread rotation (r28)
  float m = pm[0][row];
#pragma unroll
  for (int i = 1; i < 8; ++i) m = fmaxf(m, pm[i][row]);
#pragma unroll
  for (int i = 0; i < 16; ++i) {
    const int j = kg + ((i + rot) & 15);
    sc[j][row] = __expf(sc[j][row] - m);  // 0 for masked entries
  }
  __syncthreads();

  const int dg = (tid & 7) * 4;
  const float* vb = vh + (size_t)bh * Lc * HDc + dg;
  float o0a = 0.f, o1a = 0.f, o2a = 0.f, o3a = 0.f, za = 0.f;
  float o0b = 0.f, o1b = 0.f, o2b = 0.f, o3b = 0.f, zb = 0.f;
#pragma unroll 4
  for (int j = 0; j < 128; j += 2) {
    const float wa = sc[j][row];
    const float wb = sc[j + 1][row];
    za += wa; zb += wb;
    const int kca = min(max(l0 - 32 + j, 0), Lc - 1);
    const int kcb2 = min(max(l0 - 32 + j + 1, 0), Lc - 1);
    const float4 va = *(const float4*)(vb + (size_t)kca * HDc);
    const float4 vv = *(const float4*)(vb + (size_t)kcb2 * HDc);
    o0a += wa * va.x; o1a += wa * va.y; o2a += wa * va.z; o3a += wa * va.w;
    o0b += wb * vv.x; o1b += wb * vv.y; o2b += wb * vv.z; o3b += wb * vv.w;
  }
  const float iz = 1.f / (za + zb);
  *(float4*)(owin + ((size_t)bh * Lc + l0 + row) * HDc + dg) =
      make_float4((o0a + o0b) * iz, (o1a + o1b) * iz, (o2a + o2b) * iz,
                  (o3a + o3b) * iz);
}

// ---- mfma_sel role (8 waves, 2 rows/wave; r28 readlane rank scan) ----
__device__ void sel_body(unsigned char* smraw, int rowtile, int bh,
                         const unsigned short* __restrict__ qhb,
                         const unsigned short* __restrict__ khb,
                         const float* __restrict__ qh,
                         const float* __restrict__ kh,
                         const float* __restrict__ vh,
                         float* __restrict__ oslc) {
  unsigned char (*pnl)[2064] = (unsigned char(*)[2064])smraw;
  float (*candv)[16] = (float(*)[16])(smraw + 33024);
  unsigned (*candk)[128] = (unsigned(*)[128])(smraw + 33536);
  const int tid = threadIdx.x, lane = tid & 63;
  const int w = __builtin_amdgcn_readfirstlane(tid >> 6);
  const int g = lane >> 4;
  const int mn = lane & 15;
  const int r0 = rowtile * 16;

  // ---- phase A: u8 panel -> LDS (direct byte stores) ----
  const short8v qa =
      *(const short8v*)(qhb + ((size_t)bh * Lc + r0 + mn) * HDc + g * 8);
#pragma unroll
  for (int it = 0; it < 2; ++it) {
    const int k0 = w * 256 + it * 128;
    const unsigned short* kbase = khb + ((size_t)bh * Lc + k0) * HDc + g * 8;
    f32x4 acc0 = {0.f, 0.f, 0.f, 0.f}, acc1 = acc0, acc2 = acc0, acc3 = acc0;
    f32x4 acc4 = acc0, acc5 = acc0, acc6 = acc0, acc7 = acc0;
#define MM(i, dstv)                                                            \
  {                                                                            \
    const short8v kb = *(const short8v*)(kbase + (size_t)((i)*16 + mn) * HDc); \
    dstv = __builtin_amdgcn_mfma_f32_16x16x32_bf16(qa, kb, dstv, 0, 0, 0);     \
  }
    MM(0, acc0) MM(1, acc1) MM(2, acc2) MM(3, acc3)
    MM(4, acc4) MM(5, acc5) MM(6, acc6) MM(7, acc7)
#undef MM
#define QSTORE(t, accv)                                                        \
  {                                                                            \
    _Pragma("unroll") for (int r = 0; r < 4; ++r) {                            \
      const float s = accv[r] * SCALEc;                                        \
      int qi = (int)(s * 16.f + 128.f);                                        \
      qi = qi < 0 ? 0 : (qi > 255 ? 255 : qi);                                 \
      pnl[4 * g + r][k0 + (t)*16 + mn] = (unsigned char)qi;                    \
    }                                                                          \
  }
    QSTORE(0, acc0) QSTORE(1, acc1) QSTORE(2, acc2) QSTORE(3, acc3)
    QSTORE(4, acc4) QSTORE(5, acc5) QSTORE(6, acc6) QSTORE(7, acc7)
#undef QSTORE
  }
  __syncthreads();

  // ---- phase B: selection for rows 2w, 2w+1 ----
#pragma unroll 1
  for (int rr = 0; rr < 2; ++rr) {
    const int row = w * 2 + rr;
    const int l = r0 + row;
    const int r = bh * Lc + l;  // global row

    // 1. 32 u8 from LDS panel (8 conflict-free dword reads), per-lane max
    unsigned wds[8];
#pragma unroll
    for (int j = 0; j < 8; ++j)
      wds[j] = *(const unsigned*)&pnl[row][lane * 4 + j * 256];
    int q[32];
#pragma unroll
    for (int wi = 0; wi < 8; ++wi) {
      q[4 * wi + 0] = (int)(wds[wi] & 255u);
      q[4 * wi + 1] = (int)((wds[wi] >> 8) & 255u);
      q[4 * wi + 2] = (int)((wds[wi] >> 16) & 255u);
      q[4 * wi + 3] = (int)(wds[wi] >> 24);
    }
    int mq = 0;
#pragma unroll
    for (int i = 0; i < 32; ++i) mq = max(mq, q[i]);

    // 2. M16q via 8-step ballot binary search
    int T8 = 0;
#pragma unroll
    for (int b = 7; b >= 0; --b) {
      const int trial = T8 | (1 << b);
      const int c = (int)__popcll(__ballot(mq >= trial));
      if (c >= 16) T8 = trial;  // wave-uniform
    }
    const int thr = T8 - 5;  // margin: bf16 screen err + quant bucket

    // 3. bit-plane prefix compaction (no serial chain; order irrelevant —
    //    final positions come from the exact ordinal rank scan)
    unsigned hm = 0;
#pragma unroll
    for (int i = 0; i < 32; ++i) hm |= (q[i] >= thr ? 1u : 0u) << i;
    const int nh = __popc(hm);
    int pos = 0, cnt = 0;
#pragma unroll
    for (int b = 0; b < 6; ++b) {
      const unsigned long long bm = __ballot(((nh >> b) & 1) != 0);
      const int pre = (int)__builtin_amdgcn_mbcnt_hi(
          (unsigned)(bm >> 32), __builtin_amdgcn_mbcnt_lo((unsigned)bm, 0u));
      pos += pre << b;
      cnt += (int)__popcll(bm) << b;
    }
    {
      unsigned hmt = hm;
      int p = pos;
      while (hmt) {  // <= nh iters (typ. 0-2)
        const int i = __builtin_ctz(hmt);
        hmt &= hmt - 1;
        if (p < 128)
          candk[w][p] = (unsigned)((i >> 2) * 256 + lane * 4 + (i & 3));
        ++p;
      }
    }
    if (cnt > 128) cnt = 128;  // wave-uniform, >= 16
    __asm__ volatile("s_waitcnt lgkmcnt(0)" ::: "memory");

    // 4. exact f32 dots; slot B only if cnt > 64 (rare)
    const float* qp = qh + (size_t)r * HDc;
    float qr[HDc];
#pragma unroll
    for (int d = 0; d < HDc; ++d) qr[d] = qp[d] * SCALEc;
    const float* kb = kh + (size_t)bh * Lc * HDc;

    const bool vA = (lane < cnt);
    const unsigned kA = candk[w][lane];
    const float sA = dot32q(qr, kb + (size_t)(vA ? kA : 0u) * HDc);
    const u64 ordA =
        vA ? (((u64)((unsigned)f2o(sA) ^ 0x80000000u) << 12) | (u64)(2047u - kA))
           : 0ull;
    bool vB = false;
    unsigned kB = 0u;
    float sB = 0.f;
    u64 ordB = 0ull;
    if (cnt > 64) {  // wave-uniform rare path
      vB = (64 + lane < cnt);
      kB = candk[w][64 + lane];
      sB = dot32q(qr, kb + (size_t)(vB ? kB : 0u) * HDc);
      ordB = vB ? (((u64)((unsigned)f2o(sB) ^ 0x80000000u) << 12) |
                   (u64)(2047u - kB))
                : 0ull;
    }

    // 5. rank scan via readlane broadcasts (no LDS, no barriers)
    int rankA = 0, rankB = 0;
    const int c1 = cnt < 64 ? cnt : 64;
#pragma unroll 4
    for (int i = 0; i < c1; ++i) {  // wave-uniform trip count
      const u64 o = bcast64(ordA, i);
      rankA += (o > ordA) ? 1 : 0;
      rankB += (o > ordB) ? 1 : 0;
    }
    for (int i = 64; i < cnt; ++i) {  // rare (cnt > 64)
      const u64 o = bcast64(ordB, i - 64);
      rankA += (o > ordA) ? 1 : 0;
      rankB += (o > ordB) ? 1 : 0;
    }
    if (vA && rankA < 16) {
      candv[w][rankA] = sA;
      candk[w][rankA] = kA;
    }
    if (vB && rankB < 16) {
      candv[w][rankB] = sB;
      candk[w][rankB] = kB;
    }
    __asm__ volatile("s_waitcnt lgkmcnt(0)" ::: "memory");

    // 6. softmax + V gather; lane halves split winners 8/8, shfl-combine
    float mtop = candv[w][0];
#pragma unroll
    for (int i = 1; i < 16; ++i) mtop = fmaxf(mtop, candv[w][i]);
    const int d = lane & 31;
    const int kb8 = (lane >> 5) * 8;  // 0 or 8
    const float* vb = vh + (size_t)bh * Lc * HDc + d;
    float z = 0.f, oacc = 0.f;
#pragma unroll
    for (int i = 0; i < 8; ++i) {
      const float w_ = __expf(candv[w][kb8 + i] - mtop);
      z += w_;
      oacc += w_ * vb[(size_t)candk[w][kb8 + i] * HDc];
    }
    z += __shfl_xor(z, 32);
    oacc += __shfl_xor(oacc, 32);
    if (lane < 32) oslc[((size_t)bh * Lc + l) * HDc + d] = oacc / z;
  }
}

// ---- fused dispatcher: 3072 blocks, role pattern 4:1:1 per 6 blocks ----
__global__ __launch_bounds__(512) void attn_fused_kernel(
    const unsigned short* __restrict__ qhb,
    const unsigned short* __restrict__ khb,
    const float* __restrict__ qh,
    const float* __restrict__ kh,
    const float* __restrict__ vh,
    const float* __restrict__ Kcp,
    const float* __restrict__ Vcp,
    float* __restrict__ ocmp,
    float* __restrict__ oslc,
    float* __restrict__ owin) {
  __shared__ __align__(16) unsigned char smraw[SMEM_BYTES];
  const int bid = blockIdx.x;
  const int grp = bid / 6, rpos = bid % 6;  // grp in [0,512)
  if (rpos < 4) {
    const int idx = grp * 4 + rpos;  // 0..2047
    sel_body(smraw, idx & 127, idx >> 7, qhb, khb, qh, kh, vh, oslc);
  } else if (rpos == 4) {
    cmp_attn_body(smraw, grp & 31, grp >> 5, qh, Kcp, Vcp, ocmp);
  } else {
    win_attn_body(smraw, grp & 31, grp >> 5, qh, kh, vh, owin);
  }
}

// ---------- gated combine into merged (B,L,C) ----------
__global__ __launch_bounds__(256) void combine_kernel(const float* __restrict__ ocmp,
                                                      const float* __restrict__ oslc,
                                                      const float* __restrict__ owin,
                                                      const float* __restrict__ gatep,
                                                      float* __restrict__ xm) {
  const int idx = blockIdx.x * 256 + threadIdx.x;  // 4096 rows * 64 float4-groups
  const int c4 = idx & 63, grow = idx >> 6;
  const int b = grow >> 11, l = grow & 2047;
  const int h = c4 >> 3, d4 = (c4 & 7) * 4;
  const size_t hoff = (((size_t)(b * Hc + h) * Lc + l)) * HDc + d4;
  const float g0 = gatep[(size_t)grow * 3 + 0];
  const float g1 = gatep[(size_t)grow * 3 + 1];
  const float g2 = gatep[(size_t)grow * 3 + 2];
  const float4 a = *(const float4*)(ocmp + hoff);
  const float4 s = *(const float4*)(oslc + hoff);
  const float4 w = *(const float4*)(owin + hoff);
  float4 r;
  r.x = g0 * a.x + g1 * s.x + g2 * w.x;
  r.y = g0 * a.y + g1 * s.y + g2 * w.y;
  r.z = g0 * a.z + g1 * s.z + g2 * w.z;
  r.w = g0 * a.w + g1 * s.w + g2 * w.w;
  *(float4*)(xm + (size_t)grow * Cc + c4 * 4) = r;
}

// ---------- launch ----------
extern "C" void kernel_launch(void* const* d_in, const int* in_sizes, int n_in,
                              void* d_out, int out_size, void* d_ws, size_t ws_size,
                              hipStream_t stream) {
  (void)in_sizes; (void)n_in; (void)out_size; (void)ws_size;
  const float* query = (const float*)d_in[0];
  const float* key   = (const float*)d_in[1];
  const float* value = (const float*)d_in[2];
  const float* Wq = (const float*)d_in[3];
  const float* bq = (const float*)d_in[4];
  const float* Wk = (const float*)d_in[5];
  const float* bk = (const float*)d_in[6];
  const float* Wv = (const float*)d_in[7];
  const float* bv = (const float*)d_in[8];
  const float* Wo = (const float*)d_in[9];
  const float* bo = (const float*)d_in[10];
  const float* WKc = (const float*)d_in[11];
  const float* WVc = (const float*)d_in[12];
  const float* Wpe = (const float*)d_in[13];
  const float* Wg = (const float*)d_in[14];
  const float* bg = (const float*)d_in[15];

  size_t off = 0;
  auto alloc = [&](size_t bytes) -> void* {
    void* p = (char*)d_ws + off;
    off += (bytes + 255) & ~(size_t)255;
    return p;
  };
  float* qh    = (float*)alloc((size_t)TROWSc * HDc * 4);
  float* kh    = (float*)alloc((size_t)TROWSc * HDc * 4);
  float* vh    = (float*)alloc((size_t)TROWSc * HDc * 4);
  float* gatep = (float*)alloc((size_t)ROWSc * 3 * 4);
  float* Kcp   = (float*)alloc((size_t)BHc * NBc * HDc * 4);
  float* Vcp   = (float*)alloc((size_t)BHc * NBc * HDc * 4);
  float* ocmp  = (float*)alloc((size_t)TROWSc * HDc * 4);
  float* oslc  = (float*)alloc((size_t)TROWSc * HDc * 4);
  float* owin  = (float*)alloc((size_t)TROWSc * HDc * 4);
  float* xm    = (float*)alloc((size_t)ROWSc * Cc * 4);
  unsigned short* qhb = (unsigned short*)alloc((size_t)TROWSc * HDc * 2);
  unsigned short* khb = (unsigned short*)alloc((size_t)TROWSc * HDc * 2);

  proj_kernel<<<dim3(512), 256, 0, stream>>>(query, Wq, bq, qh, 1);
  proj_kernel<<<dim3(512), 256, 0, stream>>>(key, Wk, bk, kh, 1);
  proj_kernel<<<dim3(512), 256, 0, stream>>>(value, Wv, bv, vh, 1);
  gate_kernel<<<dim3(16), 256, 0, stream>>>(query, Wg, bg, gatep);
  cmpkv_kernel<<<dim3(256), 256, 0, stream>>>(kh, vh, WKc, WVc, Wpe, Kcp, Vcp);
  cvtbf16_kernel<<<dim3(2048), 256, 0, stream>>>(qh, kh, qhb, khb);
  attn_fused_kernel<<<dim3(3072), 512, 0, stream>>>(qhb, khb, qh, kh, vh, Kcp,
                                                    Vcp, ocmp, oslc, owin);
  combine_kernel<<<dim3(1024), 256, 0, stream>>>(ocmp, oslc, owin, gatep, xm);
  proj_kernel<<<dim3(512), 256, 0, stream>>>(xm, Wo, bo, (float*)d_out, 0);
}

// Round 17
// 220.032 us; speedup vs baseline: 1.0959x; 1.0959x over previous
//
#include <hip/hip_runtime.h>
#include <math.h>

// NSA attention (round 29: r27 restored (verified best, 231.1 us) + launch
// merging. Round 28 post-mortem: readlane rank-scan + rot change REGRESSED
// (241 us) -- occupancy did NOT rise despite 4-block LDS fit (so residency
// was never the limiter; per-wave latency chains govern) and conflicts did
// not drop (rotation wasn't their source). Both reverted. Safe remaining
// lever: the 10-dispatch stream has ~2-3 us gap each; merge independent
// launches with ZERO numerical change:
//  1. proj3_kernel: q/k/v projections, one launch (grid.y selects operands).
//  2. prep_kernel: gate + cmpkv + cvtbf16, one launch (block-range dispatch;
//     mutually independent, bodies byte-identical).
// Launches 10 -> 6. attn_fused = r27 exactly (fused roles 4:1:1, one-shot
// exp pass, split accumulators, bit-plane compact, LDS-ords rank scan,
// -5 margin superset, exact jax (val desc, key asc) tie order).
// B=2 L=2048 C=256 H=8 HD=32 BS=16 SK=16 win=+-32.

#define Bc 2
#define Lc 2048
#define Cc 256
#define Hc 8
#define HDc 32
#define BHc 16          // B*H
#define NBc 128         // L/BS
#define ROWSc 4096      // B*L
#define TROWSc 32768    // B*H*L
#define SCALEc 0.17677669529663687f

typedef unsigned long long u64;
typedef __attribute__((ext_vector_type(8))) short short8v;   // 8 bf16
typedef __attribute__((ext_vector_type(4))) float f32x4;

// ---------- helpers ----------

__device__ __forceinline__ float dot32q(const float* qr, const float* kr) {
  const float4* k4 = (const float4*)kr;
  float p0 = 0.f, p1 = 0.f, p2 = 0.f, p3 = 0.f;
#pragma unroll
  for (int j = 0; j < 8; j += 4) {
    float4 a = k4[j], b = k4[j + 1], c = k4[j + 2], e = k4[j + 3];
    p0 += a.x * qr[4 * j + 0] + a.y * qr[4 * j + 1] + a.z * qr[4 * j + 2] + a.w * qr[4 * j + 3];
    p1 += b.x * qr[4 * j + 4] + b.y * qr[4 * j + 5] + b.z * qr[4 * j + 6] + b.w * qr[4 * j + 7];
    p2 += c.x * qr[4 * j + 8] + c.y * qr[4 * j + 9] + c.z * qr[4 * j + 10] + c.w * qr[4 * j + 11];
    p3 += e.x * qr[4 * j + 12] + e.y * qr[4 * j + 13] + e.z * qr[4 * j + 14] + e.w * qr[4 * j + 15];
  }
  return (p0 + p1) + (p2 + p3);
}

__device__ __forceinline__ unsigned short bf16rne(float f) {
  const unsigned u = __float_as_uint(f);
  return (unsigned short)((u + 0x7fffu + ((u >> 16) & 1u)) >> 16);
}

// order-preserving float->int map
__device__ __forceinline__ int f2o(float x) {
  const int i = __float_as_int(x);
  return i >= 0 ? i : (i ^ 0x7fffffff);
}

// ---------- projection body (verified r12 structure) ----------
__device__ __forceinline__ void proj_body(const float* __restrict__ X,
                                          const float* __restrict__ W,
                                          const float* __restrict__ bias,
                                          float* __restrict__ outp,
                                          int bx, int headlayout) {
  __shared__ float xs[8 * Cc];
  const int tid = threadIdx.x;
  const int row0 = bx * 8;
  {
    const float4* xin = (const float4*)(X + (size_t)row0 * Cc);
    float4* xsv = (float4*)xs;
    xsv[tid] = xin[tid];
    xsv[tid + 256] = xin[tid + 256];
  }
  __syncthreads();
  const int c0 = (tid & 63) * 4;  // 4 consecutive cols
  const int rh = tid >> 6;        // wave id; 2 rows per wave
  float acc[2][4];
#pragma unroll
  for (int r = 0; r < 2; ++r)
#pragma unroll
    for (int c = 0; c < 4; ++c) acc[r][c] = 0.f;

#pragma unroll 4
  for (int d4 = 0; d4 < 64; ++d4) {
    const int d = d4 * 4;
    const float4 w0 = *(const float4*)(W + (size_t)(d + 0) * Cc + c0);
    const float4 w1 = *(const float4*)(W + (size_t)(d + 1) * Cc + c0);
    const float4 w2 = *(const float4*)(W + (size_t)(d + 2) * Cc + c0);
    const float4 w3 = *(const float4*)(W + (size_t)(d + 3) * Cc + c0);
#pragma unroll
    for (int r = 0; r < 2; ++r) {
      const float4 xv = *(const float4*)(xs + (rh * 2 + r) * Cc + d);
      acc[r][0] += xv.x * w0.x + xv.y * w1.x + xv.z * w2.x + xv.w * w3.x;
      acc[r][1] += xv.x * w0.y + xv.y * w1.y + xv.z * w2.y + xv.w * w3.y;
      acc[r][2] += xv.x * w0.z + xv.y * w1.z + xv.z * w2.z + xv.w * w3.z;
      acc[r][3] += xv.x * w0.w + xv.y * w1.w + xv.z * w2.w + xv.w * w3.w;
    }
  }
  const float4 bv = *(const float4*)(bias + c0);
#pragma unroll
  for (int r = 0; r < 2; ++r) {
    const int grow = row0 + rh * 2 + r;
    const float4 o = make_float4(acc[r][0] + bv.x, acc[r][1] + bv.y,
                                 acc[r][2] + bv.z, acc[r][3] + bv.w);
    if (headlayout) {
      const int b = grow >> 11, l = grow & 2047;
      const int h = c0 >> 5, dd = c0 & 31;
      *(float4*)(outp + (((size_t)(b * Hc + h) * Lc + l) * HDc + dd)) = o;
    } else {
      *(float4*)(outp + (size_t)grow * Cc + c0) = o;
    }
  }
}

// q/k/v projections in ONE launch; grid (512, 3)
__global__ __launch_bounds__(256) void proj3_kernel(
    const float* __restrict__ query, const float* __restrict__ key,
    const float* __restrict__ value, const float* __restrict__ Wq,
    const float* __restrict__ bq, const float* __restrict__ Wk,
    const float* __restrict__ bk, const float* __restrict__ Wv,
    const float* __restrict__ bv, float* __restrict__ qh,
    float* __restrict__ kh, float* __restrict__ vh) {
  const int which = blockIdx.y;
  const float* X = which == 0 ? query : (which == 1 ? key : value);
  const float* W = which == 0 ? Wq : (which == 1 ? Wk : Wv);
  const float* bias = which == 0 ? bq : (which == 1 ? bk : bv);
  float* outp = which == 0 ? qh : (which == 1 ? kh : vh);
  proj_body(X, W, bias, outp, blockIdx.x, 1);
}

// final output projection (headlayout=0)
__global__ __launch_bounds__(256) void proj_kernel(const float* __restrict__ X,
                                                   const float* __restrict__ W,
                                                   const float* __restrict__ bias,
                                                   float* __restrict__ outp) {
  proj_body(X, W, bias, outp, blockIdx.x, 0);
}

// ---------- prep: gate (16 blk) + cmpkv (256 blk) + cvtbf16 (2048 blk) ----
__global__ __launch_bounds__(256) void prep_kernel(
    const float* __restrict__ query, const float* __restrict__ Wg,
    const float* __restrict__ bg, float* __restrict__ gatep,
    const float* __restrict__ kh, const float* __restrict__ vh,
    const float* __restrict__ WKc, const float* __restrict__ WVc,
    const float* __restrict__ Wpe, float* __restrict__ Kcp,
    float* __restrict__ Vcp, const float* __restrict__ qh,
    unsigned short* __restrict__ qhb, unsigned short* __restrict__ khb) {
  const int bid = blockIdx.x;
  if (bid < 16) {
    // ---- gate body (verbatim) ----
    const int row = bid * 256 + threadIdx.x;
    const float4* x4 = (const float4*)(query + (size_t)row * Cc);
    float a0 = bg[0], a1 = bg[1], a2 = bg[2];
#pragma unroll 8
    for (int d4 = 0; d4 < 64; ++d4) {
      const float4 xv = x4[d4];
      const float* wr = Wg + d4 * 12;
      a0 += xv.x * wr[0] + xv.y * wr[3] + xv.z * wr[6] + xv.w * wr[9];
      a1 += xv.x * wr[1] + xv.y * wr[4] + xv.z * wr[7] + xv.w * wr[10];
      a2 += xv.x * wr[2] + xv.y * wr[5] + xv.z * wr[8] + xv.w * wr[11];
    }
    float* g = gatep + (size_t)row * 3;
    g[0] = 1.f / (1.f + __expf(-a0));
    g[1] = 1.f / (1.f + __expf(-a1));
    g[2] = 1.f / (1.f + __expf(-a2));
  } else if (bid < 16 + 256) {
    // ---- cmpkv body (verbatim) ----
    const int idx = (bid - 16) * 256 + threadIdx.x;  // 65536 = bh*128*32
    const int d = idx & 31, n = (idx >> 5) & 127, bh = idx >> 12;
    float pk = 0.f, pv = 0.f;
#pragma unroll
    for (int s = 0; s < 16; ++s) {
      const float pe = Wpe[s * Cc + d];
      pk += pe * WKc[s];
      pv += pe * WVc[s];
    }
    const float* kp = kh + ((size_t)bh * Lc + n * 16) * HDc + d;
    const float* vp = vh + ((size_t)bh * Lc + n * 16) * HDc + d;
    float ak = pk, av = pv;
#pragma unroll
    for (int s = 0; s < 16; ++s) {
      ak += kp[s * HDc] * WKc[s];
      av += vp[s * HDc] * WVc[s];
    }
    Kcp[idx] = ak;
    Vcp[idx] = av;
  } else {
    // ---- cvtbf16 body (verbatim) ----
    const int gid = (bid - 272) * 256 + threadIdx.x;  // 0..524287
    const int half = (TROWSc * HDc) / 4;              // 262144 float4-groups
    const float* src = gid < half ? qh : kh;
    unsigned short* dst = gid < half ? qhb : khb;
    const int i = (gid < half ? gid : gid - half) * 4;
    const float4 v = *(const float4*)(src + i);
    ushort4 o;
    o.x = bf16rne(v.x);
    o.y = bf16rne(v.y);
    o.z = bf16rne(v.z);
    o.w = bf16rne(v.w);
    *(ushort4*)(dst + i) = o;
  }
}

// ================== fused attention (role-switched, r27 verbatim) =========
// LDS arena layout:
//   sel role : pnl[16][2064] (33024) | candv[8][16] (512) | candk[8][128]
//              (4096) | ords[8][128] (8192)  = 45824 B
//   cmp/win  : sc[128][65] (33280) | pm[8][64] (2048)     = 35328 B
#define SMEM_BYTES 45824

// ---- cmp_attn role (r27: one-shot exp pass, split accumulators) ----
__device__ void cmp_attn_body(unsigned char* smraw, int bx, int bh,
                              const float* __restrict__ qh,
                              const float* __restrict__ Kcp,
                              const float* __restrict__ Vcp,
                              float* __restrict__ ocmp) {
  float (*sc)[65] = (float(*)[65])smraw;
  float (*pm)[64] = (float(*)[64])(smraw + 33280);
  const int tid = threadIdx.x, lane = tid & 63;
  const int w = __builtin_amdgcn_readfirstlane(tid >> 6);
  const int lrow = bx * 64 + lane;
  const float* q = qh + ((size_t)bh * Lc + lrow) * HDc;
  float qr[HDc];
#pragma unroll
  for (int d = 0; d < HDc; ++d) qr[d] = q[d] * SCALEc;
  const float* kcb = Kcp + (size_t)bh * NBc * HDc;
  float pmax = -1e30f;
#pragma unroll
  for (int i = 0; i < 16; ++i) {
    const int key = w * 16 + i;  // uniform
    const float s = dot32q(qr, kcb + (size_t)key * HDc);
    sc[key][lane] = s;
    pmax = fmaxf(pmax, s);
  }
  pm[w][lane] = pmax;
  __syncthreads();

  const int row = tid >> 3;        // 0..63
  const int kg = (tid & 7) * 16;   // key-group base for exp phase
  float m = pm[0][row];
#pragma unroll
  for (int i = 1; i < 8; ++i) m = fmaxf(m, pm[i][row]);
  // one-shot exp: 16 keys/thread, overwrite sc in place (rotation -> 2-way)
#pragma unroll
  for (int i = 0; i < 16; ++i) {
    const int key = kg + ((i + row) & 15);
    sc[key][row] = __expf(sc[key][row] - m);
  }
  __syncthreads();

  const int dg = (tid & 7) * 4;    // dim-group base
  const float* vcb = Vcp + (size_t)bh * NBc * HDc + dg;
  float o0a = 0.f, o1a = 0.f, o2a = 0.f, o3a = 0.f, za = 0.f;
  float o0b = 0.f, o1b = 0.f, o2b = 0.f, o3b = 0.f, zb = 0.f;
#pragma unroll 4
  for (int key = 0; key < 128; key += 2) {
    const float wa = sc[key][row];
    const float wb = sc[key + 1][row];
    za += wa; zb += wb;
    const float4 va = *(const float4*)(vcb + key * HDc);
    const float4 vv = *(const float4*)(vcb + (key + 1) * HDc);
    o0a += wa * va.x; o1a += wa * va.y; o2a += wa * va.z; o3a += wa * va.w;
    o0b += wb * vv.x; o1b += wb * vv.y; o2b += wb * vv.z; o3b += wb * vv.w;
  }
  const float iz = 1.f / (za + zb);
  *(float4*)(ocmp + ((size_t)bh * Lc + bx * 64 + row) * HDc + dg) =
      make_float4((o0a + o0b) * iz, (o1a + o1b) * iz, (o2a + o2b) * iz,
                  (o3a + o3b) * iz);
}

// ---- win_attn role (r27: one-shot exp pass, split accumulators) ----
__device__ void win_attn_body(unsigned char* smraw, int bx, int bh,
                              const float* __restrict__ qh,
                              const float* __restrict__ kh,
                              const float* __restrict__ vh,
                              float* __restrict__ owin) {
  float (*sc)[65] = (float(*)[65])smraw;
  float (*pm)[64] = (float(*)[64])(smraw + 33280);
  const int tid = threadIdx.x, lane = tid & 63;
  const int w = __builtin_amdgcn_readfirstlane(tid >> 6);
  const int l0 = bx * 64;
  const int lrow = l0 + lane;
  const float* q = qh + ((size_t)bh * Lc + lrow) * HDc;
  float qr[HDc];
#pragma unroll
  for (int d = 0; d < HDc; ++d) qr[d] = q[d] * SCALEc;
  const float* kb = kh + (size_t)bh * Lc * HDc;
  float pmax = -1e30f;
#pragma unroll
  for (int i = 0; i < 16; ++i) {
    const int j = w * 16 + i;            // 0..127 (uniform)
    const int key = l0 - 32 + j;         // absolute key (uniform)
    const int keyc = min(max(key, 0), Lc - 1);  // uniform clamp for the load
    float s = dot32q(qr, kb + (size_t)keyc * HDc);
    const int delta = key - lrow;        // lane-varying
    const bool ok = (key >= 0) && (key < Lc) && (delta >= -32) && (delta <= 32);
    s = ok ? s : -1e30f;
    sc[j][lane] = s;
    pmax = fmaxf(pmax, s);
  }
  pm[w][lane] = pmax;
  __syncthreads();

  const int row = tid >> 3;
  const int kg = (tid & 7) * 16;
  float m = pm[0][row];
#pragma unroll
  for (int i = 1; i < 8; ++i) m = fmaxf(m, pm[i][row]);
#pragma unroll
  for (int i = 0; i < 16; ++i) {
    const int j = kg + ((i + row) & 15);
    sc[j][row] = __expf(sc[j][row] - m);  // 0 for masked entries
  }
  __syncthreads();

  const int dg = (tid & 7) * 4;
  const float* vb = vh + (size_t)bh * Lc * HDc + dg;
  float o0a = 0.f, o1a = 0.f, o2a = 0.f, o3a = 0.f, za = 0.f;
  float o0b = 0.f, o1b = 0.f, o2b = 0.f, o3b = 0.f, zb = 0.f;
#pragma unroll 4
  for (int j = 0; j < 128; j += 2) {
    const float wa = sc[j][row];
    const float wb = sc[j + 1][row];
    za += wa; zb += wb;
    const int kca = min(max(l0 - 32 + j, 0), Lc - 1);
    const int kcb2 = min(max(l0 - 32 + j + 1, 0), Lc - 1);
    const float4 va = *(const float4*)(vb + (size_t)kca * HDc);
    const float4 vv = *(const float4*)(vb + (size_t)kcb2 * HDc);
    o0a += wa * va.x; o1a += wa * va.y; o2a += wa * va.z; o3a += wa * va.w;
    o0b += wb * vv.x; o1b += wb * vv.y; o2b += wb * vv.z; o3b += wb * vv.w;
  }
  const float iz = 1.f / (za + zb);
  *(float4*)(owin + ((size_t)bh * Lc + l0 + row) * HDc + dg) =
      make_float4((o0a + o0b) * iz, (o1a + o1b) * iz, (o2a + o2b) * iz,
                  (o3a + o3b) * iz);
}

// ---- mfma_sel role (8 waves, 2 rows/wave; r26 compact + r27 epilogue) ----
__device__ void sel_body(unsigned char* smraw, int rowtile, int bh,
                         const unsigned short* __restrict__ qhb,
                         const unsigned short* __restrict__ khb,
                         const float* __restrict__ qh,
                         const float* __restrict__ kh,
                         const float* __restrict__ vh,
                         float* __restrict__ oslc) {
  unsigned char (*pnl)[2064] = (unsigned char(*)[2064])smraw;
  float (*candv)[16] = (float(*)[16])(smraw + 33024);
  unsigned (*candk)[128] = (unsigned(*)[128])(smraw + 33536);
  u64 (*ords)[128] = (u64(*)[128])(smraw + 37632);
  const int tid = threadIdx.x, lane = tid & 63;
  const int w = __builtin_amdgcn_readfirstlane(tid >> 6);
  const int g = lane >> 4;
  const int mn = lane & 15;
  const int r0 = rowtile * 16;

  // ---- phase A: u8 panel -> LDS (direct byte stores) ----
  const short8v qa =
      *(const short8v*)(qhb + ((size_t)bh * Lc + r0 + mn) * HDc + g * 8);
#pragma unroll
  for (int it = 0; it < 2; ++it) {
    const int k0 = w * 256 + it * 128;
    const unsigned short* kbase = khb + ((size_t)bh * Lc + k0) * HDc + g * 8;
    f32x4 acc0 = {0.f, 0.f, 0.f, 0.f}, acc1 = acc0, acc2 = acc0, acc3 = acc0;
    f32x4 acc4 = acc0, acc5 = acc0, acc6 = acc0, acc7 = acc0;
#define MM(i, dstv)                                                            \
  {                                                                            \
    const short8v kb = *(const short8v*)(kbase + (size_t)((i)*16 + mn) * HDc); \
    dstv = __builtin_amdgcn_mfma_f32_16x16x32_bf16(qa, kb, dstv, 0, 0, 0);     \
  }
    MM(0, acc0) MM(1, acc1) MM(2, acc2) MM(3, acc3)
    MM(4, acc4) MM(5, acc5) MM(6, acc6) MM(7, acc7)
#undef MM
#define QSTORE(t, accv)                                                        \
  {                                                                            \
    _Pragma("unroll") for (int r = 0; r < 4; ++r) {                            \
      const float s = accv[r] * SCALEc;                                        \
      int qi = (int)(s * 16.f + 128.f);                                        \
      qi = qi < 0 ? 0 : (qi > 255 ? 255 : qi);                                 \
      pnl[4 * g + r][k0 + (t)*16 + mn] = (unsigned char)qi;                    \
    }                                                                          \
  }
    QSTORE(0, acc0) QSTORE(1, acc1) QSTORE(2, acc2) QSTORE(3, acc3)
    QSTORE(4, acc4) QSTORE(5, acc5) QSTORE(6, acc6) QSTORE(7, acc7)
#undef QSTORE
  }
  __syncthreads();

  // ---- phase B: selection for rows 2w, 2w+1 ----
#pragma unroll 1
  for (int rr = 0; rr < 2; ++rr) {
    const int row = w * 2 + rr;
    const int l = r0 + row;
    const int r = bh * Lc + l;  // global row

    // 1. 32 u8 from LDS panel (8 conflict-free dword reads), per-lane max
    unsigned wds[8];
#pragma unroll
    for (int j = 0; j < 8; ++j)
      wds[j] = *(const unsigned*)&pnl[row][lane * 4 + j * 256];
    int q[32];
#pragma unroll
    for (int wi = 0; wi < 8; ++wi) {
      q[4 * wi + 0] = (int)(wds[wi] & 255u);
      q[4 * wi + 1] = (int)((wds[wi] >> 8) & 255u);
      q[4 * wi + 2] = (int)((wds[wi] >> 16) & 255u);
      q[4 * wi + 3] = (int)(wds[wi] >> 24);
    }
    int mq = 0;
#pragma unroll
    for (int i = 0; i < 32; ++i) mq = max(mq, q[i]);

    // 2. M16q via 8-step ballot binary search
    int T8 = 0;
#pragma unroll
    for (int b = 7; b >= 0; --b) {
      const int trial = T8 | (1 << b);
      const int c = (int)__popcll(__ballot(mq >= trial));
      if (c >= 16) T8 = trial;  // wave-uniform
    }
    const int thr = T8 - 5;  // margin: bf16 screen err + quant bucket

    // 3. bit-plane prefix compaction (no serial chain; order irrelevant —
    //    final positions come from the exact ordinal rank scan)
    unsigned hm = 0;
#pragma unroll
    for (int i = 0; i < 32; ++i) hm |= (q[i] >= thr ? 1u : 0u) << i;
    const int nh = __popc(hm);
    int pos = 0, cnt = 0;
#pragma unroll
    for (int b = 0; b < 6; ++b) {
      const unsigned long long bm = __ballot(((nh >> b) & 1) != 0);
      const int pre = (int)__builtin_amdgcn_mbcnt_hi(
          (unsigned)(bm >> 32), __builtin_amdgcn_mbcnt_lo((unsigned)bm, 0u));
      pos += pre << b;
      cnt += (int)__popcll(bm) << b;
    }
    {
      unsigned hmt = hm;
      int p = pos;
      while (hmt) {  // <= nh iters (typ. 0-2)
        const int i = __builtin_ctz(hmt);
        hmt &= hmt - 1;
        if (p < 128)
          candk[w][p] = (unsigned)((i >> 2) * 256 + lane * 4 + (i & 3));
        ++p;
      }
    }
    if (cnt > 128) cnt = 128;  // wave-uniform, >= 16
    __asm__ volatile("s_waitcnt lgkmcnt(0)" ::: "memory");

    // 4. exact f32 dots; slot B only if cnt > 64 (rare)
    const float* qp = qh + (size_t)r * HDc;
    float qr[HDc];
#pragma unroll
    for (int d = 0; d < HDc; ++d) qr[d] = qp[d] * SCALEc;
    const float* kb = kh + (size_t)bh * Lc * HDc;

    const bool vA = (lane < cnt);
    const unsigned kA = candk[w][lane];
    const float sA = dot32q(qr, kb + (size_t)(vA ? kA : 0u) * HDc);
    const u64 ordA =
        vA ? (((u64)((unsigned)f2o(sA) ^ 0x80000000u) << 12) | (u64)(2047u - kA))
           : 0ull;
    bool vB = false;
    unsigned kB = 0u;
    float sB = 0.f;
    u64 ordB = 0ull;
    if (cnt > 64) {  // wave-uniform rare path
      vB = (64 + lane < cnt);
      kB = candk[w][64 + lane];
      sB = dot32q(qr, kb + (size_t)(vB ? kB : 0u) * HDc);
      ordB = vB ? (((u64)((unsigned)f2o(sB) ^ 0x80000000u) << 12) |
                   (u64)(2047u - kB))
                : 0ull;
    }

    // 5. rank scan (parallel across lanes, no serial chain)
    ords[w][lane] = ordA;
    ords[w][64 + lane] = ordB;
    __asm__ volatile("s_waitcnt lgkmcnt(0)" ::: "memory");
    int rankA = 0, rankB = 0;
#pragma unroll 4
    for (int i = 0; i < cnt; ++i) {  // wave-uniform trip count
      const u64 o = ords[w][i];      // same addr all lanes -> LDS broadcast
      rankA += (o > ordA) ? 1 : 0;
      rankB += (o > ordB) ? 1 : 0;
    }
    if (vA && rankA < 16) {
      candv[w][rankA] = sA;
      candk[w][rankA] = kA;
    }
    if (vB && rankB < 16) {
      candv[w][rankB] = sB;
      candk[w][rankB] = kB;
    }
    __asm__ volatile("s_waitcnt lgkmcnt(0)" ::: "memory");

    // 6. softmax + V gather; lane halves split winners 8/8, shfl-combine
    float mtop = candv[w][0];
#pragma unroll
    for (int i = 1; i < 16; ++i) mtop = fmaxf(mtop, candv[w][i]);
    const int d = lane & 31;
    const int kb8 = (lane >> 5) * 8;  // 0 or 8
    const float* vb = vh + (size_t)bh * Lc * HDc + d;
    float z = 0.f, oacc = 0.f;
#pragma unroll
    for (int i = 0; i < 8; ++i) {
      const float w_ = __expf(candv[w][kb8 + i] - mtop);
      z += w_;
      oacc += w_ * vb[(size_t)candk[w][kb8 + i] * HDc];
    }
    z += __shfl_xor(z, 32);
    oacc += __shfl_xor(oacc, 32);
    if (lane < 32) oslc[((size_t)bh * Lc + l) * HDc + d] = oacc / z;
  }
}

// ---- fused dispatcher: 3072 blocks, role pattern 4:1:1 per 6 blocks ----
__global__ __launch_bounds__(512) void attn_fused_kernel(
    const unsigned short* __restrict__ qhb,
    const unsigned short* __restrict__ khb,
    const float* __restrict__ qh,
    const float* __restrict__ kh,
    const float* __restrict__ vh,
    const float* __restrict__ Kcp,
    const float* __restrict__ Vcp,
    float* __restrict__ ocmp,
    float* __restrict__ oslc,
    float* __restrict__ owin) {
  __shared__ __align__(16) unsigned char smraw[SMEM_BYTES];
  const int bid = blockIdx.x;
  const int grp = bid / 6, rpos = bid % 6;  // grp in [0,512)
  if (rpos < 4) {
    const int idx = grp * 4 + rpos;  // 0..2047
    sel_body(smraw, idx & 127, idx >> 7, qhb, khb, qh, kh, vh, oslc);
  } else if (rpos == 4) {
    cmp_attn_body(smraw, grp & 31, grp >> 5, qh, Kcp, Vcp, ocmp);
  } else {
    win_attn_body(smraw, grp & 31, grp >> 5, qh, kh, vh, owin);
  }
}

// ---------- gated combine into merged (B,L,C) ----------
__global__ __launch_bounds__(256) void combine_kernel(const float* __restrict__ ocmp,
                                                      const float* __restrict__ oslc,
                                                      const float* __restrict__ owin,
                                                      const float* __restrict__ gatep,
                                                      float* __restrict__ xm) {
  const int idx = blockIdx.x * 256 + threadIdx.x;  // 4096 rows * 64 float4-groups
  const int c4 = idx & 63, grow = idx >> 6;
  const int b = grow >> 11, l = grow & 2047;
  const int h = c4 >> 3, d4 = (c4 & 7) * 4;
  const size_t hoff = (((size_t)(b * Hc + h) * Lc + l)) * HDc + d4;
  const float g0 = gatep[(size_t)grow * 3 + 0];
  const float g1 = gatep[(size_t)grow * 3 + 1];
  const float g2 = gatep[(size_t)grow * 3 + 2];
  const float4 a = *(const float4*)(ocmp + hoff);
  const float4 s = *(const float4*)(oslc + hoff);
  const float4 w = *(const float4*)(owin + hoff);
  float4 r;
  r.x = g0 * a.x + g1 * s.x + g2 * w.x;
  r.y = g0 * a.y + g1 * s.y + g2 * w.y;
  r.z = g0 * a.z + g1 * s.z + g2 * w.z;
  r.w = g0 * a.w + g1 * s.w + g2 * w.w;
  *(float4*)(xm + (size_t)grow * Cc + c4 * 4) = r;
}

// ---------- launch ----------
extern "C" void kernel_launch(void* const* d_in, const int* in_sizes, int n_in,
                              void* d_out, int out_size, void* d_ws, size_t ws_size,
                              hipStream_t stream) {
  (void)in_sizes; (void)n_in; (void)out_size; (void)ws_size;
  const float* query = (const float*)d_in[0];
  const float* key   = (const float*)d_in[1];
  const float* value = (const float*)d_in[2];
  const float* Wq = (const float*)d_in[3];
  const float* bq = (const float*)d_in[4];
  const float* Wk = (const float*)d_in[5];
  const float* bk = (const float*)d_in[6];
  const float* Wv = (const float*)d_in[7];
  const float* bv = (const float*)d_in[8];
  const float* Wo = (const float*)d_in[9];
  const float* bo = (const float*)d_in[10];
  const float* WKc = (const float*)d_in[11];
  const float* WVc = (const float*)d_in[12];
  const float* Wpe = (const float*)d_in[13];
  const float* Wg = (const float*)d_in[14];
  const float* bg = (const float*)d_in[15];

  size_t off = 0;
  auto alloc = [&](size_t bytes) -> void* {
    void* p = (char*)d_ws + off;
    off += (bytes + 255) & ~(size_t)255;
    return p;
  };
  float* qh    = (float*)alloc((size_t)TROWSc * HDc * 4);
  float* kh    = (float*)alloc((size_t)TROWSc * HDc * 4);
  float* vh    = (float*)alloc((size_t)TROWSc * HDc * 4);
  float* gatep = (float*)alloc((size_t)ROWSc * 3 * 4);
  float* Kcp   = (float*)alloc((size_t)BHc * NBc * HDc * 4);
  float* Vcp   = (float*)alloc((size_t)BHc * NBc * HDc * 4);
  float* ocmp  = (float*)alloc((size_t)TROWSc * HDc * 4);
  float* oslc  = (float*)alloc((size_t)TROWSc * HDc * 4);
  float* owin  = (float*)alloc((size_t)TROWSc * HDc * 4);
  float* xm    = (float*)alloc((size_t)ROWSc * Cc * 4);
  unsigned short* qhb = (unsigned short*)alloc((size_t)TROWSc * HDc * 2);
  unsigned short* khb = (unsigned short*)alloc((size_t)TROWSc * HDc * 2);

  proj3_kernel<<<dim3(512, 3), 256, 0, stream>>>(query, key, value, Wq, bq, Wk,
                                                 bk, Wv, bv, qh, kh, vh);
  prep_kernel<<<dim3(2320), 256, 0, stream>>>(query, Wg, bg, gatep, kh, vh,
                                              WKc, WVc, Wpe, Kcp, Vcp, qh, qhb,
                                              khb);
  attn_fused_kernel<<<dim3(3072), 512, 0, stream>>>(qhb, khb, qh, kh, vh, Kcp,
                                                    Vcp, ocmp, oslc, owin);
  combine_kernel<<<dim3(1024), 256, 0, stream>>>(ocmp, oslc, owin, gatep, xm);
  proj_kernel<<<dim3(512), 256, 0, stream>>>(xm, Wo, bo, (float*)d_out);
}

// Round 18
// 217.341 us; speedup vs baseline: 1.1094x; 1.0124x over previous
//
#include <hip/hip_runtime.h>
#include <math.h>

// NSA attention (round 30: combine fused into the output projection.
// Round 29 verified: launch merging 10->6 gave 231->220 us exactly as
// predicted (pure gap removal; attn_fused profile unchanged). Also learned:
// the 1.58M bank conflicts are ~2% of cycles -- not worth chasing. Same
// lever again: combine_kernel writes xm (4MB) which proj immediately
// re-stages into LDS. Fuse: combineproj_kernel computes the gated combine
// DIRECTLY into the proj staging buffer (identical f32 formula/order ->
// bit-identical xs contents), then runs the unchanged proj math. Deletes
// one launch + gap + 8MB HBM round-trip + the xm buffer. Launches 5 -> 4.
// attn_fused and all selection machinery byte-identical to r29 (verified:
// -5 margin superset, bit-plane compact, LDS-ords rank scan = exact jax
// (val desc, key asc) tie order, one-shot exp pass, split accumulators).
// B=2 L=2048 C=256 H=8 HD=32 BS=16 SK=16 win=+-32.

#define Bc 2
#define Lc 2048
#define Cc 256
#define Hc 8
#define HDc 32
#define BHc 16          // B*H
#define NBc 128         // L/BS
#define ROWSc 4096      // B*L
#define TROWSc 32768    // B*H*L
#define SCALEc 0.17677669529663687f

typedef unsigned long long u64;
typedef __attribute__((ext_vector_type(8))) short short8v;   // 8 bf16
typedef __attribute__((ext_vector_type(4))) float f32x4;

// ---------- helpers ----------

__device__ __forceinline__ float dot32q(const float* qr, const float* kr) {
  const float4* k4 = (const float4*)kr;
  float p0 = 0.f, p1 = 0.f, p2 = 0.f, p3 = 0.f;
#pragma unroll
  for (int j = 0; j < 8; j += 4) {
    float4 a = k4[j], b = k4[j + 1], c = k4[j + 2], e = k4[j + 3];
    p0 += a.x * qr[4 * j + 0] + a.y * qr[4 * j + 1] + a.z * qr[4 * j + 2] + a.w * qr[4 * j + 3];
    p1 += b.x * qr[4 * j + 4] + b.y * qr[4 * j + 5] + b.z * qr[4 * j + 6] + b.w * qr[4 * j + 7];
    p2 += c.x * qr[4 * j + 8] + c.y * qr[4 * j + 9] + c.z * qr[4 * j + 10] + c.w * qr[4 * j + 11];
    p3 += e.x * qr[4 * j + 12] + e.y * qr[4 * j + 13] + e.z * qr[4 * j + 14] + e.w * qr[4 * j + 15];
  }
  return (p0 + p1) + (p2 + p3);
}

__device__ __forceinline__ unsigned short bf16rne(float f) {
  const unsigned u = __float_as_uint(f);
  return (unsigned short)((u + 0x7fffu + ((u >> 16) & 1u)) >> 16);
}

// order-preserving float->int map
__device__ __forceinline__ int f2o(float x) {
  const int i = __float_as_int(x);
  return i >= 0 ? i : (i ^ 0x7fffffff);
}

// ---------- projection math on staged xs (verified r12 structure) ----------
__device__ __forceinline__ void proj_math(const float* __restrict__ xs,
                                          const float* __restrict__ W,
                                          const float* __restrict__ bias,
                                          float* __restrict__ outp,
                                          int bx, int headlayout) {
  const int tid = threadIdx.x;
  const int row0 = bx * 8;
  const int c0 = (tid & 63) * 4;  // 4 consecutive cols
  const int rh = tid >> 6;        // wave id; 2 rows per wave
  float acc[2][4];
#pragma unroll
  for (int r = 0; r < 2; ++r)
#pragma unroll
    for (int c = 0; c < 4; ++c) acc[r][c] = 0.f;

#pragma unroll 4
  for (int d4 = 0; d4 < 64; ++d4) {
    const int d = d4 * 4;
    const float4 w0 = *(const float4*)(W + (size_t)(d + 0) * Cc + c0);
    const float4 w1 = *(const float4*)(W + (size_t)(d + 1) * Cc + c0);
    const float4 w2 = *(const float4*)(W + (size_t)(d + 2) * Cc + c0);
    const float4 w3 = *(const float4*)(W + (size_t)(d + 3) * Cc + c0);
#pragma unroll
    for (int r = 0; r < 2; ++r) {
      const float4 xv = *(const float4*)(xs + (rh * 2 + r) * Cc + d);
      acc[r][0] += xv.x * w0.x + xv.y * w1.x + xv.z * w2.x + xv.w * w3.x;
      acc[r][1] += xv.x * w0.y + xv.y * w1.y + xv.z * w2.y + xv.w * w3.y;
      acc[r][2] += xv.x * w0.z + xv.y * w1.z + xv.z * w2.z + xv.w * w3.z;
      acc[r][3] += xv.x * w0.w + xv.y * w1.w + xv.z * w2.w + xv.w * w3.w;
    }
  }
  const float4 bv = *(const float4*)(bias + c0);
#pragma unroll
  for (int r = 0; r < 2; ++r) {
    const int grow = row0 + rh * 2 + r;
    const float4 o = make_float4(acc[r][0] + bv.x, acc[r][1] + bv.y,
                                 acc[r][2] + bv.z, acc[r][3] + bv.w);
    if (headlayout) {
      const int b = grow >> 11, l = grow & 2047;
      const int h = c0 >> 5, dd = c0 & 31;
      *(float4*)(outp + (((size_t)(b * Hc + h) * Lc + l) * HDc + dd)) = o;
    } else {
      *(float4*)(outp + (size_t)grow * Cc + c0) = o;
    }
  }
}

// q/k/v projections in ONE launch; grid (512, 3)
__global__ __launch_bounds__(256) void proj3_kernel(
    const float* __restrict__ query, const float* __restrict__ key,
    const float* __restrict__ value, const float* __restrict__ Wq,
    const float* __restrict__ bq, const float* __restrict__ Wk,
    const float* __restrict__ bk, const float* __restrict__ Wv,
    const float* __restrict__ bv, float* __restrict__ qh,
    float* __restrict__ kh, float* __restrict__ vh) {
  __shared__ float xs[8 * Cc];
  const int which = blockIdx.y;
  const float* X = which == 0 ? query : (which == 1 ? key : value);
  const float* W = which == 0 ? Wq : (which == 1 ? Wk : Wv);
  const float* bias = which == 0 ? bq : (which == 1 ? bk : bv);
  float* outp = which == 0 ? qh : (which == 1 ? kh : vh);
  const int tid = threadIdx.x;
  {
    const float4* xin = (const float4*)(X + (size_t)blockIdx.x * 8 * Cc);
    float4* xsv = (float4*)xs;
    xsv[tid] = xin[tid];
    xsv[tid + 256] = xin[tid + 256];
  }
  __syncthreads();
  proj_math(xs, W, bias, outp, blockIdx.x, 1);
}

// gated combine (inline, bit-identical to the old combine_kernel) + output
// projection; grid (512)
__global__ __launch_bounds__(256) void combineproj_kernel(
    const float* __restrict__ ocmp, const float* __restrict__ oslc,
    const float* __restrict__ owin, const float* __restrict__ gatep,
    const float* __restrict__ Wo, const float* __restrict__ bo,
    float* __restrict__ outp) {
  __shared__ float xs[8 * Cc];
  const int tid = threadIdx.x;
  const int row0 = blockIdx.x * 8;
#pragma unroll
  for (int t = 0; t < 2; ++t) {
    const int idx = tid + t * 256;        // 0..511 float4-groups
    const int r = idx >> 6, c4 = idx & 63;
    const int grow = row0 + r;
    const int b = grow >> 11, l = grow & 2047;
    const int h = c4 >> 3, d4 = (c4 & 7) * 4;
    const size_t hoff = (((size_t)(b * Hc + h) * Lc + l)) * HDc + d4;
    const float g0 = gatep[(size_t)grow * 3 + 0];
    const float g1 = gatep[(size_t)grow * 3 + 1];
    const float g2 = gatep[(size_t)grow * 3 + 2];
    const float4 a = *(const float4*)(ocmp + hoff);
    const float4 s = *(const float4*)(oslc + hoff);
    const float4 w = *(const float4*)(owin + hoff);
    float4 rr;
    rr.x = g0 * a.x + g1 * s.x + g2 * w.x;
    rr.y = g0 * a.y + g1 * s.y + g2 * w.y;
    rr.z = g0 * a.z + g1 * s.z + g2 * w.z;
    rr.w = g0 * a.w + g1 * s.w + g2 * w.w;
    *(float4*)(xs + (size_t)idx * 4) = rr;
  }
  __syncthreads();
  proj_math(xs, Wo, bo, outp, blockIdx.x, 0);
}

// ---------- prep: gate (16 blk) + cmpkv (256 blk) + cvtbf16 (2048 blk) ----
__global__ __launch_bounds__(256) void prep_kernel(
    const float* __restrict__ query, const float* __restrict__ Wg,
    const float* __restrict__ bg, float* __restrict__ gatep,
    const float* __restrict__ kh, const float* __restrict__ vh,
    const float* __restrict__ WKc, const float* __restrict__ WVc,
    const float* __restrict__ Wpe, float* __restrict__ Kcp,
    float* __restrict__ Vcp, const float* __restrict__ qh,
    unsigned short* __restrict__ qhb, unsigned short* __restrict__ khb) {
  const int bid = blockIdx.x;
  if (bid < 16) {
    // ---- gate body (verbatim) ----
    const int row = bid * 256 + threadIdx.x;
    const float4* x4 = (const float4*)(query + (size_t)row * Cc);
    float a0 = bg[0], a1 = bg[1], a2 = bg[2];
#pragma unroll 8
    for (int d4 = 0; d4 < 64; ++d4) {
      const float4 xv = x4[d4];
      const float* wr = Wg + d4 * 12;
      a0 += xv.x * wr[0] + xv.y * wr[3] + xv.z * wr[6] + xv.w * wr[9];
      a1 += xv.x * wr[1] + xv.y * wr[4] + xv.z * wr[7] + xv.w * wr[10];
      a2 += xv.x * wr[2] + xv.y * wr[5] + xv.z * wr[8] + xv.w * wr[11];
    }
    float* g = gatep + (size_t)row * 3;
    g[0] = 1.f / (1.f + __expf(-a0));
    g[1] = 1.f / (1.f + __expf(-a1));
    g[2] = 1.f / (1.f + __expf(-a2));
  } else if (bid < 16 + 256) {
    // ---- cmpkv body (verbatim) ----
    const int idx = (bid - 16) * 256 + threadIdx.x;  // 65536 = bh*128*32
    const int d = idx & 31, n = (idx >> 5) & 127, bh = idx >> 12;
    float pk = 0.f, pv = 0.f;
#pragma unroll
    for (int s = 0; s < 16; ++s) {
      const float pe = Wpe[s * Cc + d];
      pk += pe * WKc[s];
      pv += pe * WVc[s];
    }
    const float* kp = kh + ((size_t)bh * Lc + n * 16) * HDc + d;
    const float* vp = vh + ((size_t)bh * Lc + n * 16) * HDc + d;
    float ak = pk, av = pv;
#pragma unroll
    for (int s = 0; s < 16; ++s) {
      ak += kp[s * HDc] * WKc[s];
      av += vp[s * HDc] * WVc[s];
    }
    Kcp[idx] = ak;
    Vcp[idx] = av;
  } else {
    // ---- cvtbf16 body (verbatim) ----
    const int gid = (bid - 272) * 256 + threadIdx.x;  // 0..524287
    const int half = (TROWSc * HDc) / 4;              // 262144 float4-groups
    const float* src = gid < half ? qh : kh;
    unsigned short* dst = gid < half ? qhb : khb;
    const int i = (gid < half ? gid : gid - half) * 4;
    const float4 v = *(const float4*)(src + i);
    ushort4 o;
    o.x = bf16rne(v.x);
    o.y = bf16rne(v.y);
    o.z = bf16rne(v.z);
    o.w = bf16rne(v.w);
    *(ushort4*)(dst + i) = o;
  }
}

// ================== fused attention (role-switched, r27 verbatim) =========
// LDS arena layout:
//   sel role : pnl[16][2064] (33024) | candv[8][16] (512) | candk[8][128]
//              (4096) | ords[8][128] (8192)  = 45824 B
//   cmp/win  : sc[128][65] (33280) | pm[8][64] (2048)     = 35328 B
#define SMEM_BYTES 45824

// ---- cmp_attn role (r27: one-shot exp pass, split accumulators) ----
__device__ void cmp_attn_body(unsigned char* smraw, int bx, int bh,
                              const float* __restrict__ qh,
                              const float* __restrict__ Kcp,
                              const float* __restrict__ Vcp,
                              float* __restrict__ ocmp) {
  float (*sc)[65] = (float(*)[65])smraw;
  float (*pm)[64] = (float(*)[64])(smraw + 33280);
  const int tid = threadIdx.x, lane = tid & 63;
  const int w = __builtin_amdgcn_readfirstlane(tid >> 6);
  const int lrow = bx * 64 + lane;
  const float* q = qh + ((size_t)bh * Lc + lrow) * HDc;
  float qr[HDc];
#pragma unroll
  for (int d = 0; d < HDc; ++d) qr[d] = q[d] * SCALEc;
  const float* kcb = Kcp + (size_t)bh * NBc * HDc;
  float pmax = -1e30f;
#pragma unroll
  for (int i = 0; i < 16; ++i) {
    const int key = w * 16 + i;  // uniform
    const float s = dot32q(qr, kcb + (size_t)key * HDc);
    sc[key][lane] = s;
    pmax = fmaxf(pmax, s);
  }
  pm[w][lane] = pmax;
  __syncthreads();

  const int row = tid >> 3;        // 0..63
  const int kg = (tid & 7) * 16;   // key-group base for exp phase
  float m = pm[0][row];
#pragma unroll
  for (int i = 1; i < 8; ++i) m = fmaxf(m, pm[i][row]);
  // one-shot exp: 16 keys/thread, overwrite sc in place (rotation -> 2-way)
#pragma unroll
  for (int i = 0; i < 16; ++i) {
    const int key = kg + ((i + row) & 15);
    sc[key][row] = __expf(sc[key][row] - m);
  }
  __syncthreads();

  const int dg = (tid & 7) * 4;    // dim-group base
  const float* vcb = Vcp + (size_t)bh * NBc * HDc + dg;
  float o0a = 0.f, o1a = 0.f, o2a = 0.f, o3a = 0.f, za = 0.f;
  float o0b = 0.f, o1b = 0.f, o2b = 0.f, o3b = 0.f, zb = 0.f;
#pragma unroll 4
  for (int key = 0; key < 128; key += 2) {
    const float wa = sc[key][row];
    const float wb = sc[key + 1][row];
    za += wa; zb += wb;
    const float4 va = *(const float4*)(vcb + key * HDc);
    const float4 vv = *(const float4*)(vcb + (key + 1) * HDc);
    o0a += wa * va.x; o1a += wa * va.y; o2a += wa * va.z; o3a += wa * va.w;
    o0b += wb * vv.x; o1b += wb * vv.y; o2b += wb * vv.z; o3b += wb * vv.w;
  }
  const float iz = 1.f / (za + zb);
  *(float4*)(ocmp + ((size_t)bh * Lc + bx * 64 + row) * HDc + dg) =
      make_float4((o0a + o0b) * iz, (o1a + o1b) * iz, (o2a + o2b) * iz,
                  (o3a + o3b) * iz);
}

// ---- win_attn role (r27: one-shot exp pass, split accumulators) ----
__device__ void win_attn_body(unsigned char* smraw, int bx, int bh,
                              const float* __restrict__ qh,
                              const float* __restrict__ kh,
                              const float* __restrict__ vh,
                              float* __restrict__ owin) {
  float (*sc)[65] = (float(*)[65])smraw;
  float (*pm)[64] = (float(*)[64])(smraw + 33280);
  const int tid = threadIdx.x, lane = tid & 63;
  const int w = __builtin_amdgcn_readfirstlane(tid >> 6);
  const int l0 = bx * 64;
  const int lrow = l0 + lane;
  const float* q = qh + ((size_t)bh * Lc + lrow) * HDc;
  float qr[HDc];
#pragma unroll
  for (int d = 0; d < HDc; ++d) qr[d] = q[d] * SCALEc;
  const float* kb = kh + (size_t)bh * Lc * HDc;
  float pmax = -1e30f;
#pragma unroll
  for (int i = 0; i < 16; ++i) {
    const int j = w * 16 + i;            // 0..127 (uniform)
    const int key = l0 - 32 + j;         // absolute key (uniform)
    const int keyc = min(max(key, 0), Lc - 1);  // uniform clamp for the load
    float s = dot32q(qr, kb + (size_t)keyc * HDc);
    const int delta = key - lrow;        // lane-varying
    const bool ok = (key >= 0) && (key < Lc) && (delta >= -32) && (delta <= 32);
    s = ok ? s : -1e30f;
    sc[j][lane] = s;
    pmax = fmaxf(pmax, s);
  }
  pm[w][lane] = pmax;
  __syncthreads();

  const int row = tid >> 3;
  const int kg = (tid & 7) * 16;
  float m = pm[0][row];
#pragma unroll
  for (int i = 1; i < 8; ++i) m = fmaxf(m, pm[i][row]);
#pragma unroll
  for (int i = 0; i < 16; ++i) {
    const int j = kg + ((i + row) & 15);
    sc[j][row] = __expf(sc[j][row] - m);  // 0 for masked entries
  }
  __syncthreads();

  const int dg = (tid & 7) * 4;
  const float* vb = vh + (size_t)bh * Lc * HDc + dg;
  float o0a = 0.f, o1a = 0.f, o2a = 0.f, o3a = 0.f, za = 0.f;
  float o0b = 0.f, o1b = 0.f, o2b = 0.f, o3b = 0.f, zb = 0.f;
#pragma unroll 4
  for (int j = 0; j < 128; j += 2) {
    const float wa = sc[j][row];
    const float wb = sc[j + 1][row];
    za += wa; zb += wb;
    const int kca = min(max(l0 - 32 + j, 0), Lc - 1);
    const int kcb2 = min(max(l0 - 32 + j + 1, 0), Lc - 1);
    const float4 va = *(const float4*)(vb + (size_t)kca * HDc);
    const float4 vv = *(const float4*)(vb + (size_t)kcb2 * HDc);
    o0a += wa * va.x; o1a += wa * va.y; o2a += wa * va.z; o3a += wa * va.w;
    o0b += wb * vv.x; o1b += wb * vv.y; o2b += wb * vv.z; o3b += wb * vv.w;
  }
  const float iz = 1.f / (za + zb);
  *(float4*)(owin + ((size_t)bh * Lc + l0 + row) * HDc + dg) =
      make_float4((o0a + o0b) * iz, (o1a + o1b) * iz, (o2a + o2b) * iz,
                  (o3a + o3b) * iz);
}

// ---- mfma_sel role (8 waves, 2 rows/wave; r26 compact + r27 epilogue) ----
__device__ void sel_body(unsigned char* smraw, int rowtile, int bh,
                         const unsigned short* __restrict__ qhb,
                         const unsigned short* __restrict__ khb,
                         const float* __restrict__ qh,
                         const float* __restrict__ kh,
                         const float* __restrict__ vh,
                         float* __restrict__ oslc) {
  unsigned char (*pnl)[2064] = (unsigned char(*)[2064])smraw;
  float (*candv)[16] = (float(*)[16])(smraw + 33024);
  unsigned (*candk)[128] = (unsigned(*)[128])(smraw + 33536);
  u64 (*ords)[128] = (u64(*)[128])(smraw + 37632);
  const int tid = threadIdx.x, lane = tid & 63;
  const int w = __builtin_amdgcn_readfirstlane(tid >> 6);
  const int g = lane >> 4;
  const int mn = lane & 15;
  const int r0 = rowtile * 16;

  // ---- phase A: u8 panel -> LDS (direct byte stores) ----
  const short8v qa =
      *(const short8v*)(qhb + ((size_t)bh * Lc + r0 + mn) * HDc + g * 8);
#pragma unroll
  for (int it = 0; it < 2; ++it) {
    const int k0 = w * 256 + it * 128;
    const unsigned short* kbase = khb + ((size_t)bh * Lc + k0) * HDc + g * 8;
    f32x4 acc0 = {0.f, 0.f, 0.f, 0.f}, acc1 = acc0, acc2 = acc0, acc3 = acc0;
    f32x4 acc4 = acc0, acc5 = acc0, acc6 = acc0, acc7 = acc0;
#define MM(i, dstv)                                                            \
  {                                                                            \
    const short8v kb = *(const short8v*)(kbase + (size_t)((i)*16 + mn) * HDc); \
    dstv = __builtin_amdgcn_mfma_f32_16x16x32_bf16(qa, kb, dstv, 0, 0, 0);     \
  }
    MM(0, acc0) MM(1, acc1) MM(2, acc2) MM(3, acc3)
    MM(4, acc4) MM(5, acc5) MM(6, acc6) MM(7, acc7)
#undef MM
#define QSTORE(t, accv)                                                        \
  {                                                                            \
    _Pragma("unroll") for (int r = 0; r < 4; ++r) {                            \
      const float s = accv[r] * SCALEc;                                        \
      int qi = (int)(s * 16.f + 128.f);                                        \
      qi = qi < 0 ? 0 : (qi > 255 ? 255 : qi);                                 \
      pnl[4 * g + r][k0 + (t)*16 + mn] = (unsigned char)qi;                    \
    }                                                                          \
  }
    QSTORE(0, acc0) QSTORE(1, acc1) QSTORE(2, acc2) QSTORE(3, acc3)
    QSTORE(4, acc4) QSTORE(5, acc5) QSTORE(6, acc6) QSTORE(7, acc7)
#undef QSTORE
  }
  __syncthreads();

  // ---- phase B: selection for rows 2w, 2w+1 ----
#pragma unroll 1
  for (int rr = 0; rr < 2; ++rr) {
    const int row = w * 2 + rr;
    const int l = r0 + row;
    const int r = bh * Lc + l;  // global row

    // 1. 32 u8 from LDS panel (8 conflict-free dword reads), per-lane max
    unsigned wds[8];
#pragma unroll
    for (int j = 0; j < 8; ++j)
      wds[j] = *(const unsigned*)&pnl[row][lane * 4 + j * 256];
    int q[32];
#pragma unroll
    for (int wi = 0; wi < 8; ++wi) {
      q[4 * wi + 0] = (int)(wds[wi] & 255u);
      q[4 * wi + 1] = (int)((wds[wi] >> 8) & 255u);
      q[4 * wi + 2] = (int)((wds[wi] >> 16) & 255u);
      q[4 * wi + 3] = (int)(wds[wi] >> 24);
    }
    int mq = 0;
#pragma unroll
    for (int i = 0; i < 32; ++i) mq = max(mq, q[i]);

    // 2. M16q via 8-step ballot binary search
    int T8 = 0;
#pragma unroll
    for (int b = 7; b >= 0; --b) {
      const int trial = T8 | (1 << b);
      const int c = (int)__popcll(__ballot(mq >= trial));
      if (c >= 16) T8 = trial;  // wave-uniform
    }
    const int thr = T8 - 5;  // margin: bf16 screen err + quant bucket

    // 3. bit-plane prefix compaction (no serial chain; order irrelevant —
    //    final positions come from the exact ordinal rank scan)
    unsigned hm = 0;
#pragma unroll
    for (int i = 0; i < 32; ++i) hm |= (q[i] >= thr ? 1u : 0u) << i;
    const int nh = __popc(hm);
    int pos = 0, cnt = 0;
#pragma unroll
    for (int b = 0; b < 6; ++b) {
      const unsigned long long bm = __ballot(((nh >> b) & 1) != 0);
      const int pre = (int)__builtin_amdgcn_mbcnt_hi(
          (unsigned)(bm >> 32), __builtin_amdgcn_mbcnt_lo((unsigned)bm, 0u));
      pos += pre << b;
      cnt += (int)__popcll(bm) << b;
    }
    {
      unsigned hmt = hm;
      int p = pos;
      while (hmt) {  // <= nh iters (typ. 0-2)
        const int i = __builtin_ctz(hmt);
        hmt &= hmt - 1;
        if (p < 128)
          candk[w][p] = (unsigned)((i >> 2) * 256 + lane * 4 + (i & 3));
        ++p;
      }
    }
    if (cnt > 128) cnt = 128;  // wave-uniform, >= 16
    __asm__ volatile("s_waitcnt lgkmcnt(0)" ::: "memory");

    // 4. exact f32 dots; slot B only if cnt > 64 (rare)
    const float* qp = qh + (size_t)r * HDc;
    float qr[HDc];
#pragma unroll
    for (int d = 0; d < HDc; ++d) qr[d] = qp[d] * SCALEc;
    const float* kb = kh + (size_t)bh * Lc * HDc;

    const bool vA = (lane < cnt);
    const unsigned kA = candk[w][lane];
    const float sA = dot32q(qr, kb + (size_t)(vA ? kA : 0u) * HDc);
    const u64 ordA =
        vA ? (((u64)((unsigned)f2o(sA) ^ 0x80000000u) << 12) | (u64)(2047u - kA))
           : 0ull;
    bool vB = false;
    unsigned kB = 0u;
    float sB = 0.f;
    u64 ordB = 0ull;
    if (cnt > 64) {  // wave-uniform rare path
      vB = (64 + lane < cnt);
      kB = candk[w][64 + lane];
      sB = dot32q(qr, kb + (size_t)(vB ? kB : 0u) * HDc);
      ordB = vB ? (((u64)((unsigned)f2o(sB) ^ 0x80000000u) << 12) |
                   (u64)(2047u - kB))
                : 0ull;
    }

    // 5. rank scan (parallel across lanes, no serial chain)
    ords[w][lane] = ordA;
    ords[w][64 + lane] = ordB;
    __asm__ volatile("s_waitcnt lgkmcnt(0)" ::: "memory");
    int rankA = 0, rankB = 0;
#pragma unroll 4
    for (int i = 0; i < cnt; ++i) {  // wave-uniform trip count
      const u64 o = ords[w][i];      // same addr all lanes -> LDS broadcast
      rankA += (o > ordA) ? 1 : 0;
      rankB += (o > ordB) ? 1 : 0;
    }
    if (vA && rankA < 16) {
      candv[w][rankA] = sA;
      candk[w][rankA] = kA;
    }
    if (vB && rankB < 16) {
      candv[w][rankB] = sB;
      candk[w][rankB] = kB;
    }
    __asm__ volatile("s_waitcnt lgkmcnt(0)" ::: "memory");

    // 6. softmax + V gather; lane halves split winners 8/8, shfl-combine
    float mtop = candv[w][0];
#pragma unroll
    for (int i = 1; i < 16; ++i) mtop = fmaxf(mtop, candv[w][i]);
    const int d = lane & 31;
    const int kb8 = (lane >> 5) * 8;  // 0 or 8
    const float* vb = vh + (size_t)bh * Lc * HDc + d;
    float z = 0.f, oacc = 0.f;
#pragma unroll
    for (int i = 0; i < 8; ++i) {
      const float w_ = __expf(candv[w][kb8 + i] - mtop);
      z += w_;
      oacc += w_ * vb[(size_t)candk[w][kb8 + i] * HDc];
    }
    z += __shfl_xor(z, 32);
    oacc += __shfl_xor(oacc, 32);
    if (lane < 32) oslc[((size_t)bh * Lc + l) * HDc + d] = oacc / z;
  }
}

// ---- fused dispatcher: 3072 blocks, role pattern 4:1:1 per 6 blocks ----
__global__ __launch_bounds__(512) void attn_fused_kernel(
    const unsigned short* __restrict__ qhb,
    const unsigned short* __restrict__ khb,
    const float* __restrict__ qh,
    const float* __restrict__ kh,
    const float* __restrict__ vh,
    const float* __restrict__ Kcp,
    const float* __restrict__ Vcp,
    float* __restrict__ ocmp,
    float* __restrict__ oslc,
    float* __restrict__ owin) {
  __shared__ __align__(16) unsigned char smraw[SMEM_BYTES];
  const int bid = blockIdx.x;
  const int grp = bid / 6, rpos = bid % 6;  // grp in [0,512)
  if (rpos < 4) {
    const int idx = grp * 4 + rpos;  // 0..2047
    sel_body(smraw, idx & 127, idx >> 7, qhb, khb, qh, kh, vh, oslc);
  } else if (rpos == 4) {
    cmp_attn_body(smraw, grp & 31, grp >> 5, qh, Kcp, Vcp, ocmp);
  } else {
    win_attn_body(smraw, grp & 31, grp >> 5, qh, kh, vh, owin);
  }
}

// ---------- launch ----------
extern "C" void kernel_launch(void* const* d_in, const int* in_sizes, int n_in,
                              void* d_out, int out_size, void* d_ws, size_t ws_size,
                              hipStream_t stream) {
  (void)in_sizes; (void)n_in; (void)out_size; (void)ws_size;
  const float* query = (const float*)d_in[0];
  const float* key   = (const float*)d_in[1];
  const float* value = (const float*)d_in[2];
  const float* Wq = (const float*)d_in[3];
  const float* bq = (const float*)d_in[4];
  const float* Wk = (const float*)d_in[5];
  const float* bk = (const float*)d_in[6];
  const float* Wv = (const float*)d_in[7];
  const float* bv = (const float*)d_in[8];
  const float* Wo = (const float*)d_in[9];
  const float* bo = (const float*)d_in[10];
  const float* WKc = (const float*)d_in[11];
  const float* WVc = (const float*)d_in[12];
  const float* Wpe = (const float*)d_in[13];
  const float* Wg = (const float*)d_in[14];
  const float* bg = (const float*)d_in[15];

  size_t off = 0;
  auto alloc = [&](size_t bytes) -> void* {
    void* p = (char*)d_ws + off;
    off += (bytes + 255) & ~(size_t)255;
    return p;
  };
  float* qh    = (float*)alloc((size_t)TROWSc * HDc * 4);
  float* kh    = (float*)alloc((size_t)TROWSc * HDc * 4);
  float* vh    = (float*)alloc((size_t)TROWSc * HDc * 4);
  float* gatep = (float*)alloc((size_t)ROWSc * 3 * 4);
  float* Kcp   = (float*)alloc((size_t)BHc * NBc * HDc * 4);
  float* Vcp   = (float*)alloc((size_t)BHc * NBc * HDc * 4);
  float* ocmp  = (float*)alloc((size_t)TROWSc * HDc * 4);
  float* oslc  = (float*)alloc((size_t)TROWSc * HDc * 4);
  float* owin  = (float*)alloc((size_t)TROWSc * HDc * 4);
  unsigned short* qhb = (unsigned short*)alloc((size_t)TROWSc * HDc * 2);
  unsigned short* khb = (unsigned short*)alloc((size_t)TROWSc * HDc * 2);

  proj3_kernel<<<dim3(512, 3), 256, 0, stream>>>(query, key, value, Wq, bq, Wk,
                                                 bk, Wv, bv, qh, kh, vh);
  prep_kernel<<<dim3(2320), 256, 0, stream>>>(query, Wg, bg, gatep, kh, vh,
                                              WKc, WVc, Wpe, Kcp, Vcp, qh, qhb,
                                              khb);
  attn_fused_kernel<<<dim3(3072), 512, 0, stream>>>(qhb, khb, qh, kh, vh, Kcp,
                                                    Vcp, ocmp, oslc, owin);
  combineproj_kernel<<<dim3(512), 256, 0, stream>>>(ocmp, oslc, owin, gatep,
                                                    Wo, bo, (float*)d_out);
}